// Round 1
// baseline (1813.185 us; speedup 1.0000x reference)
//
#include <hip/hip_runtime.h>

#define HH 256       // hidden size
#define NB 64        // batch (segments)
#define ROWS 64      // rows per block tile
#define NTOT 262144  // NK == NC

// ---------------------------------------------------------------------------
// Heavy fused layer: actT <- (optional relu)(actT^T @ W + b)^T, in place.
// actT is [HH][ROWS] (k-major, transposed activations) in LDS.
// 256 threads: thread = (rt = tid&7 -> rows rt*8..+7, ct = tid>>3 -> cols ct*8..+7)
// 64 fp32 accumulators per thread. Weights streamed from global (L1/L2 cached).
// ---------------------------------------------------------------------------
template<bool RELU>
__device__ __forceinline__ void heavy_layer(float* actT, const float* __restrict__ W,
                                            const float* __restrict__ bias, int tid)
{
  const int rt = tid & 7;
  const int ct = tid >> 3;
  const int r0 = rt * 8;
  const int j0 = ct * 8;

  float acc[8][8];
  {
    float bb[8];
#pragma unroll
    for (int m = 0; m < 8; ++m) bb[m] = bias[j0 + m];
#pragma unroll
    for (int i = 0; i < 8; ++i)
#pragma unroll
      for (int m = 0; m < 8; ++m) acc[i][m] = bb[m];
  }

  const float4* actv = (const float4*)actT;  // row k: 16 float4
  const float4* Wv   = (const float4*)W;     // row k: 64 float4

#pragma unroll 4
  for (int k = 0; k < HH; ++k) {
    float4 a0 = actv[k * 16 + rt * 2];
    float4 a1 = actv[k * 16 + rt * 2 + 1];
    float4 w0 = Wv[k * 64 + ct * 2];
    float4 w1 = Wv[k * 64 + ct * 2 + 1];
    float av[8] = {a0.x, a0.y, a0.z, a0.w, a1.x, a1.y, a1.z, a1.w};
    float wv[8] = {w0.x, w0.y, w0.z, w0.w, w1.x, w1.y, w1.z, w1.w};
#pragma unroll
    for (int i = 0; i < 8; ++i)
#pragma unroll
      for (int m = 0; m < 8; ++m)
        acc[i][m] = fmaf(av[i], wv[m], acc[i][m]);
  }

  __syncthreads();  // everyone done READING actT before overwrite

#pragma unroll
  for (int m = 0; m < 8; ++m) {
    float4 v0, v1;
    v0.x = acc[0][m]; v0.y = acc[1][m]; v0.z = acc[2][m]; v0.w = acc[3][m];
    v1.x = acc[4][m]; v1.y = acc[5][m]; v1.z = acc[6][m]; v1.w = acc[7][m];
    if (RELU) {
      v0.x = fmaxf(v0.x, 0.f); v0.y = fmaxf(v0.y, 0.f);
      v0.z = fmaxf(v0.z, 0.f); v0.w = fmaxf(v0.w, 0.f);
      v1.x = fmaxf(v1.x, 0.f); v1.y = fmaxf(v1.y, 0.f);
      v1.z = fmaxf(v1.z, 0.f); v1.w = fmaxf(v1.w, 0.f);
    }
    float4* dst = (float4*)(actT + (j0 + m) * ROWS + r0);
    dst[0] = v0;
    dst[1] = v1;
  }
  __syncthreads();
}

// layer 1: F=3 -> H with relu. thread = column j; row order rotated by j to
// avoid the 32-way LDS write conflict (stride-64 rows land in one bank).
__device__ __forceinline__ void layer1(float* actT, const float* xs,
                                       const float* __restrict__ W0,
                                       const float* __restrict__ b0, int tid)
{
  const int j = tid;
  float w0 = W0[j], w1 = W0[HH + j], w2 = W0[2 * HH + j], b = b0[j];
  for (int rr = 0; rr < ROWS; ++rr) {
    int r = (rr + j) & (ROWS - 1);
    float a = fmaf(xs[r * 3 + 2], w2,
                   fmaf(xs[r * 3 + 1], w1, fmaf(xs[r * 3], w0, b)));
    actT[j * ROWS + r] = fmaxf(a, 0.f);
  }
}

// ---------------------------------------------------------------------------
__global__ __launch_bounds__(256, 2)
void trunk_kernel(const float* __restrict__ nodes, const int* __restrict__ coord_seg,
                  const float* __restrict__ tw0, const float* __restrict__ tb0,
                  const float* __restrict__ tw1, const float* __restrict__ tb1,
                  const float* __restrict__ tw2, const float* __restrict__ tb2,
                  float* __restrict__ seg_sum)
{
  __shared__ float actT[HH * ROWS];
  __shared__ float xs[ROWS * 3];
  __shared__ int   segs[ROWS];
  const int tid = threadIdx.x;
  const int r0g = blockIdx.x * ROWS;

  if (tid < ROWS * 3) xs[tid] = nodes[r0g * 3 + tid];
  if (tid < ROWS) segs[tid] = coord_seg[r0g + tid];
  __syncthreads();

  layer1(actT, xs, tw0, tb0, tid);
  __syncthreads();
  heavy_layer<true >(actT, tw1, tb1, tid);
  heavy_layer<false>(actT, tw2, tb2, tid);  // c (no relu)

  // per-segment sums of c, thread = column j (segs sorted -> few distinct)
  {
    const int j = tid;
    const int s_lo = segs[0], s_hi = segs[ROWS - 1];
    for (int s = s_lo; s <= s_hi; ++s) {
      float p = 0.f;
      for (int rr = 0; rr < ROWS; ++rr) {
        int r = (rr + j) & (ROWS - 1);
        if (segs[r] == s) p += actT[j * ROWS + r];
      }
      atomicAdd(&seg_sum[s * HH + j], p);
    }
  }
}

__global__ __launch_bounds__(256, 2)
void branch_kernel(const float* __restrict__ known_nodes, const int* __restrict__ known_seg,
                   const float* __restrict__ bw0, const float* __restrict__ bb0,
                   const float* __restrict__ bw1, const float* __restrict__ bb1,
                   const float* __restrict__ bw2, const float* __restrict__ bb2,
                   const float* __restrict__ seg_mean,
                   const float* __restrict__ ow0, const float* __restrict__ ob0,
                   const float* __restrict__ ow1, const float* __restrict__ ob1,
                   float* __restrict__ out)
{
  __shared__ float actT[HH * ROWS];
  __shared__ float xs[ROWS * 3];
  __shared__ int   segs[ROWS];
  const int tid = threadIdx.x;
  const int r0g = blockIdx.x * ROWS;

  if (tid < ROWS * 3) xs[tid] = known_nodes[r0g * 3 + tid];
  if (tid < ROWS) segs[tid] = known_seg[r0g + tid];
  __syncthreads();

  layer1(actT, xs, bw0, bb0, tid);
  __syncthreads();
  heavy_layer<true >(actT, bw1, bb1, tid);
  heavy_layer<false>(actT, bw2, bb2, tid);  // f (no relu)

  // feat = f * seg_mean[seg]  (in place on actT)
  {
    const int j = tid;
    for (int rr = 0; rr < ROWS; ++rr) {
      int r = (rr + j) & (ROWS - 1);
      actT[j * ROWS + r] *= seg_mean[segs[r] * HH + j];
    }
  }
  __syncthreads();

  heavy_layer<true>(actT, ow0, ob0, tid);  // h = relu(feat @ ow0 + ob0)

  // out = h @ ow1 + ob1   (256 -> 3), thread = row
  if (tid < ROWS) {
    const int r = tid;
    float o0 = ob1[0], o1 = ob1[1], o2 = ob1[2];
    for (int k = 0; k < HH; ++k) {
      float a = actT[k * ROWS + r];
      o0 = fmaf(a, ow1[k * 3 + 0], o0);
      o1 = fmaf(a, ow1[k * 3 + 1], o1);
      o2 = fmaf(a, ow1[k * 3 + 2], o2);
    }
    float* dst = out + (size_t)(r0g + r) * 3;
    dst[0] = o0; dst[1] = o1; dst[2] = o2;
  }
}

__global__ void zero_kernel(float* __restrict__ p, int n)
{
  int i = blockIdx.x * blockDim.x + threadIdx.x;
  if (i < n) p[i] = 0.f;
}

__global__ void mean_kernel(const float* __restrict__ seg_sum,
                            const int* __restrict__ coord_seg,
                            float* __restrict__ seg_mean)
{
  const int b = blockIdx.x;  // one block per segment
  // count of b in sorted coord_seg via two binary searches (uniform -> scalar)
  int lo = 0, n = NTOT;
  while (n > 0) { int h = n >> 1; int mid = lo + h;
    if (coord_seg[mid] < b) { lo = mid + 1; n -= h + 1; } else n = h; }
  int hi = lo; n = NTOT - lo;
  while (n > 0) { int h = n >> 1; int mid = hi + h;
    if (coord_seg[mid] < b + 1) { hi = mid + 1; n -= h + 1; } else n = h; }
  float cnt = (float)(hi - lo);
  float inv = 1.0f / fmaxf(cnt, 1.0f);
  seg_mean[b * HH + threadIdx.x] = seg_sum[b * HH + threadIdx.x] * inv;
}

// ---------------------------------------------------------------------------
extern "C" void kernel_launch(void* const* d_in, const int* in_sizes, int n_in,
                              void* d_out, int out_size, void* d_ws, size_t ws_size,
                              hipStream_t stream)
{
  const float* known_nodes = (const float*)d_in[0];
  const float* nodes       = (const float*)d_in[1];
  const int*   known_seg   = (const int*)d_in[2];
  const int*   coord_seg   = (const int*)d_in[3];
  const float* bw0 = (const float*)d_in[4];
  const float* bb0 = (const float*)d_in[5];
  const float* bw1 = (const float*)d_in[6];
  const float* bb1 = (const float*)d_in[7];
  const float* bw2 = (const float*)d_in[8];
  const float* bb2 = (const float*)d_in[9];
  const float* tw0 = (const float*)d_in[10];
  const float* tb0 = (const float*)d_in[11];
  const float* tw1 = (const float*)d_in[12];
  const float* tb1 = (const float*)d_in[13];
  const float* tw2 = (const float*)d_in[14];
  const float* tb2 = (const float*)d_in[15];
  const float* ow0 = (const float*)d_in[16];
  const float* ob0 = (const float*)d_in[17];
  const float* ow1 = (const float*)d_in[18];
  const float* ob1 = (const float*)d_in[19];

  float* out      = (float*)d_out;
  float* seg_sum  = (float*)d_ws;            // [64][256]
  float* seg_mean = seg_sum + NB * HH;       // [64][256]

  zero_kernel<<<(NB * HH + 255) / 256, 256, 0, stream>>>(seg_sum, NB * HH);
  trunk_kernel<<<NTOT / ROWS, 256, 0, stream>>>(nodes, coord_seg,
                                                tw0, tb0, tw1, tb1, tw2, tb2,
                                                seg_sum);
  mean_kernel<<<NB, 256, 0, stream>>>(seg_sum, coord_seg, seg_mean);
  branch_kernel<<<NTOT / ROWS, 256, 0, stream>>>(known_nodes, known_seg,
                                                 bw0, bb0, bw1, bb1, bw2, bb2,
                                                 seg_mean,
                                                 ow0, ob0, ow1, ob1,
                                                 out);
}

// Round 3
// 456.038 us; speedup vs baseline: 3.9760x; 3.9760x over previous
//
#include <hip/hip_runtime.h>

#define HH 256       // hidden size
#define NB 64        // batch (segments)
#define ROWS 128     // rows per block tile
#define NTOT 262144  // NK == NC
#define THREADS 512  // 8 waves

typedef _Float16 half8 __attribute__((ext_vector_type(8)));
typedef _Float16 half4 __attribute__((ext_vector_type(4)));
typedef float f32x4 __attribute__((ext_vector_type(4)));

// act LDS tile: [row][k] fp16, 128 rows x 256 k = 64KB, stride 512B.
// XOR swizzle (G4): spreads stride-512B rows across banks; preserves 16B/8B
// alignment (only bit4 flipped).
__device__ __forceinline__ uint32_t swz(uint32_t r, uint32_t k) {
  return ((r << 9) + (k << 1)) ^ ((r & 7) << 4);
}

// ---------------------------------------------------------------------------
// Heavy layer via MFMA, swapped operands:
//   D[m=j][n=r] = sum_k WT[j][k] * act[r][k]
// A-frag (weights): lane l -> WT[j0+jf*16+(l&15)][ks*32+(l>>4)*8 .. +8]  (16B global)
// B-frag (act):     lane l -> act[r0+rf*16+(l&15)][ks*32+(l>>4)*8 .. +8] (16B LDS)
// D-frag: r = l&15, j = (l>>4)*4 + reg  -> 4 consecutive j per lane -> 8B LDS write.
// Per wave: 64r x 64j tile = 4x4 fragments, K=256 in 8 steps, 128 MFMAs.
// ---------------------------------------------------------------------------
template<bool RELU>
__device__ __forceinline__ void heavy_layer(char* act, const _Float16* __restrict__ WT,
                                            const float* __restrict__ bias, int tid)
{
  const int wid  = tid >> 6;
  const int lane = tid & 63;
  const int lr   = lane & 15;
  const int lg   = lane >> 4;
  const int r0   = (wid & 1) << 6;
  const int j0   = (wid >> 1) << 6;

  f32x4 acc[4][4];  // [jf][rf]
#pragma unroll
  for (int jf = 0; jf < 4; ++jf)
#pragma unroll
    for (int rf = 0; rf < 4; ++rf)
      acc[jf][rf] = (f32x4){0.f, 0.f, 0.f, 0.f};

  const _Float16* wbase = WT + (j0 + lr) * HH + lg * 8;

#pragma unroll 2
  for (int ks = 0; ks < 8; ++ks) {
    half8 b[4];
#pragma unroll
    for (int rf = 0; rf < 4; ++rf)
      b[rf] = *(const half8*)(act + swz(r0 + rf * 16 + lr, ks * 32 + lg * 8));
#pragma unroll
    for (int jf = 0; jf < 4; ++jf) {
      half8 a = *(const half8*)(wbase + jf * 16 * HH + ks * 32);
#pragma unroll
      for (int rf = 0; rf < 4; ++rf)
        acc[jf][rf] = __builtin_amdgcn_mfma_f32_16x16x32_f16(a, b[rf], acc[jf][rf], 0, 0, 0);
    }
  }

  __syncthreads();  // all waves done READING act before overwrite

#pragma unroll
  for (int jf = 0; jf < 4; ++jf) {
    f32x4 bj = *(const f32x4*)(bias + j0 + jf * 16 + lg * 4);
#pragma unroll
    for (int rf = 0; rf < 4; ++rf) {
      f32x4 v = acc[jf][rf] + bj;
      half4 h;
#pragma unroll
      for (int u = 0; u < 4; ++u) {
        float x = v[u];
        if (RELU) x = fmaxf(x, 0.f);
        h[u] = (_Float16)x;
      }
      *(half4*)(act + swz(r0 + rf * 16 + lr, j0 + jf * 16 + lg * 4)) = h;
    }
  }
  __syncthreads();
}

// layer 1: F=3 -> H (relu), fp32 VALU, writes fp16 act.
// thread = (j = tid&255, half = tid>>8 -> 64 rows). xs reads are wave-uniform
// (broadcast from L1), no LDS needed.
__device__ __forceinline__ void layer1(char* act, const float* __restrict__ nodes,
                                       int r0g, const float* __restrict__ W0,
                                       const float* __restrict__ b0, int tid)
{
  const int j  = tid & 255;
  const int rb = (tid >> 8) * 64;
  const float w0 = W0[j], w1 = W0[HH + j], w2 = W0[2 * HH + j], b = b0[j];
  for (int rr = 0; rr < 64; ++rr) {
    int r = rb + rr;
    const float* x = nodes + (size_t)(r0g + r) * 3;
    float a = fmaf(x[2], w2, fmaf(x[1], w1, fmaf(x[0], w0, b)));
    a = fmaxf(a, 0.f);
    *(_Float16*)(act + swz(r, j)) = (_Float16)a;
  }
}

// ---------------------------------------------------------------------------
__global__ __launch_bounds__(THREADS, 4)
void trunk_kernel(const float* __restrict__ nodes, const int* __restrict__ coord_seg,
                  const float* __restrict__ tw0, const float* __restrict__ tb0,
                  const _Float16* __restrict__ wt1, const float* __restrict__ tb1,
                  const _Float16* __restrict__ wt2, const float* __restrict__ tb2,
                  float* __restrict__ seg_sum)
{
  __shared__ __align__(16) char act[ROWS * HH * 2];  // 64KB exactly
  const int tid = threadIdx.x;
  const int r0g = blockIdx.x * ROWS;

  layer1(act, nodes, r0g, tw0, tb0, tid);
  __syncthreads();
  heavy_layer<true >(act, wt1, tb1, tid);
  heavy_layer<false>(act, wt2, tb2, tid);  // c (no relu)

  // per-segment sums of c; segs sorted -> 1-2 distinct per 64-row half.
  {
    const int j  = tid & 255;
    const int rb = (tid >> 8) * 64;
    const int s_lo = coord_seg[r0g + rb];
    const int s_hi = coord_seg[r0g + rb + 63];
    for (int s = s_lo; s <= s_hi; ++s) {
      float p = 0.f;
      for (int rr = 0; rr < 64; ++rr) {
        int r = rb + rr;
        if (coord_seg[r0g + r] == s)
          p += (float)*(const _Float16*)(act + swz(r, j));
      }
      atomicAdd(&seg_sum[s * HH + j], p);
    }
  }
}

__global__ __launch_bounds__(THREADS, 4)
void branch_kernel(const float* __restrict__ known_nodes, const int* __restrict__ known_seg,
                   const float* __restrict__ bw0, const float* __restrict__ bb0,
                   const _Float16* __restrict__ wt1, const float* __restrict__ bb1,
                   const _Float16* __restrict__ wt2, const float* __restrict__ bb2,
                   const float* __restrict__ seg_mean,
                   const _Float16* __restrict__ wto, const float* __restrict__ ob0,
                   const float* __restrict__ ow1, const float* __restrict__ ob1,
                   float* __restrict__ out)
{
  __shared__ __align__(16) char act[ROWS * HH * 2];
  const int tid = threadIdx.x;
  const int r0g = blockIdx.x * ROWS;

  layer1(act, known_nodes, r0g, bw0, bb0, tid);
  __syncthreads();
  heavy_layer<true >(act, wt1, bb1, tid);
  heavy_layer<false>(act, wt2, bb2, tid);  // f (no relu)

  // feat = f * seg_mean[seg]  (in place, fp16)
  {
    const int j  = tid & 255;
    const int rb = (tid >> 8) * 64;
    for (int rr = 0; rr < 64; ++rr) {
      int r = rb + rr;
      int s = known_seg[r0g + r];  // uniform across the 256 j-lanes
      _Float16* p = (_Float16*)(act + swz(r, j));
      *p = (_Float16)((float)*p * seg_mean[s * HH + j]);
    }
  }
  __syncthreads();

  heavy_layer<true>(act, wto, ob0, tid);  // h = relu(feat @ ow0 + ob0)

  // out = h @ ow1 + ob1  (256 -> 3); thread = row, vector fp16 reads.
  if (tid < ROWS) {
    const int r = tid;
    float o0 = ob1[0], o1 = ob1[1], o2 = ob1[2];
    for (int k = 0; k < HH; k += 8) {
      half8 h = *(const half8*)(act + swz(r, k));
#pragma unroll
      for (int u = 0; u < 8; ++u) {
        float a = (float)h[u];
        o0 = fmaf(a, ow1[(k + u) * 3 + 0], o0);
        o1 = fmaf(a, ow1[(k + u) * 3 + 1], o1);
        o2 = fmaf(a, ow1[(k + u) * 3 + 2], o2);
      }
    }
    float* dst = out + (size_t)(r0g + r) * 3;
    dst[0] = o0; dst[1] = o1; dst[2] = o2;
  }
}

// W[256][256] fp32 row-major -> WT[j][k] fp16 (5 matrices), once per launch.
struct WPtrs { const float* w[5]; _Float16* wt[5]; };
__global__ void transpose_kernel(WPtrs p)
{
  const int m = blockIdx.x >> 8;   // matrix
  const int j = blockIdx.x & 255;  // output row
  const int k = threadIdx.x;       // 256 threads, coalesced writes
  p.wt[m][j * HH + k] = (_Float16)p.w[m][k * HH + j];
}

__global__ void zero_kernel(float* __restrict__ p, int n)
{
  int i = blockIdx.x * blockDim.x + threadIdx.x;
  if (i < n) p[i] = 0.f;
}

__global__ void mean_kernel(const float* __restrict__ seg_sum,
                            const int* __restrict__ coord_seg,
                            float* __restrict__ seg_mean)
{
  const int b = blockIdx.x;
  int lo = 0, n = NTOT;
  while (n > 0) { int h = n >> 1; int mid = lo + h;
    if (coord_seg[mid] < b) { lo = mid + 1; n -= h + 1; } else n = h; }
  int hi = lo; n = NTOT - lo;
  while (n > 0) { int h = n >> 1; int mid = hi + h;
    if (coord_seg[mid] < b + 1) { hi = mid + 1; n -= h + 1; } else n = h; }
  float inv = 1.0f / fmaxf((float)(hi - lo), 1.0f);
  seg_mean[b * HH + threadIdx.x] = seg_sum[b * HH + threadIdx.x] * inv;
}

// ---------------------------------------------------------------------------
extern "C" void kernel_launch(void* const* d_in, const int* in_sizes, int n_in,
                              void* d_out, int out_size, void* d_ws, size_t ws_size,
                              hipStream_t stream)
{
  const float* known_nodes = (const float*)d_in[0];
  const float* nodes       = (const float*)d_in[1];
  const int*   known_seg   = (const int*)d_in[2];
  const int*   coord_seg   = (const int*)d_in[3];
  const float* bw0 = (const float*)d_in[4];
  const float* bb0 = (const float*)d_in[5];
  const float* bw1 = (const float*)d_in[6];
  const float* bb1 = (const float*)d_in[7];
  const float* bw2 = (const float*)d_in[8];
  const float* bb2 = (const float*)d_in[9];
  const float* tw0 = (const float*)d_in[10];
  const float* tb0 = (const float*)d_in[11];
  const float* tw1 = (const float*)d_in[12];
  const float* tb1 = (const float*)d_in[13];
  const float* tw2 = (const float*)d_in[14];
  const float* tb2 = (const float*)d_in[15];
  const float* ow0 = (const float*)d_in[16];
  const float* ob0 = (const float*)d_in[17];
  const float* ow1 = (const float*)d_in[18];
  const float* ob1 = (const float*)d_in[19];

  float* out      = (float*)d_out;
  float* seg_sum  = (float*)d_ws;                        // [64][256] f32
  float* seg_mean = seg_sum + NB * HH;                   // [64][256] f32
  _Float16* wtb   = (_Float16*)((char*)d_ws + (size_t)2 * NB * HH * 4);
  _Float16* wt_tw1 = wtb + 0 * HH * HH;
  _Float16* wt_tw2 = wtb + 1 * HH * HH;
  _Float16* wt_bw1 = wtb + 2 * HH * HH;
  _Float16* wt_bw2 = wtb + 3 * HH * HH;
  _Float16* wt_ow0 = wtb + 4 * HH * HH;

  WPtrs wp;
  wp.w[0] = tw1; wp.wt[0] = wt_tw1;
  wp.w[1] = tw2; wp.wt[1] = wt_tw2;
  wp.w[2] = bw1; wp.wt[2] = wt_bw1;
  wp.w[3] = bw2; wp.wt[3] = wt_bw2;
  wp.w[4] = ow0; wp.wt[4] = wt_ow0;

  transpose_kernel<<<5 * 256, 256, 0, stream>>>(wp);
  zero_kernel<<<(NB * HH + 255) / 256, 256, 0, stream>>>(seg_sum, NB * HH);
  trunk_kernel<<<NTOT / ROWS, THREADS, 0, stream>>>(nodes, coord_seg,
                                                    tw0, tb0, wt_tw1, tb1, wt_tw2, tb2,
                                                    seg_sum);
  mean_kernel<<<NB, 256, 0, stream>>>(seg_sum, coord_seg, seg_mean);
  branch_kernel<<<NTOT / ROWS, THREADS, 0, stream>>>(known_nodes, known_seg,
                                                     bw0, bb0, wt_bw1, bb1, wt_bw2, bb2,
                                                     seg_mean,
                                                     wt_ow0, ob0, ow1, ob1,
                                                     out);
}

// Round 4
// 380.769 us; speedup vs baseline: 4.7619x; 1.1977x over previous
//
#include <hip/hip_runtime.h>

#define HH 256       // hidden size
#define NB 64        // batch (segments)
#define ROWS 64      // rows per block tile
#define NTOT 262144  // NK == NC
#define THREADS 256  // 4 waves

typedef _Float16 half8 __attribute__((ext_vector_type(8)));
typedef _Float16 half4 __attribute__((ext_vector_type(4)));
typedef float f32x4 __attribute__((ext_vector_type(4)));

// act LDS tile: [row][k] fp16, 64 rows x 256 k = 32KB, row stride 512B.
// Bijective XOR swizzle: r and r+8 land in distinct bank slots, so 8B writes
// (16 lanes/cy, r=0..15) and 16B reads (8 lanes/cy, r=0..7 / 8..15) are
// conflict-free. Flips bits 4-6 only -> 16B/8B alignment preserved.
__device__ __forceinline__ uint32_t swz(uint32_t r, uint32_t k) {
  return (((r << 9) + (k << 1)) ^ ((r & 7) << 4)) ^ ((r & 8) << 3);
}

// ---------------------------------------------------------------------------
// Heavy layer via MFMA, swapped operands:
//   D[m=j][n=r] = sum_k WT[j][k] * act[r][k]
// A-frag (weights): lane l -> WT[j0+jf*16+(l&15)][ks*32+(l>>4)*8 .. +8] (16B L2)
// B-frag (act):     lane l -> act[rf*16+(l&15)][ks*32+(l>>4)*8 .. +8]   (16B LDS)
// D-frag: r = l&15, j = (l>>4)*4 + reg -> 4 consecutive j per lane -> 8B write.
// Wave tile: 64r x 64j (j0 = wid*64) -> weight matrix read exactly once/block.
// ---------------------------------------------------------------------------
template<bool RELU>
__device__ __forceinline__ void heavy_layer(char* act, const _Float16* __restrict__ WT,
                                            const float* __restrict__ bias, int tid)
{
  const int wid  = tid >> 6;
  const int lane = tid & 63;
  const int lr   = lane & 15;
  const int lg   = lane >> 4;
  const int j0   = wid << 6;

  f32x4 acc[4][4];  // [jf][rf]
#pragma unroll
  for (int jf = 0; jf < 4; ++jf)
#pragma unroll
    for (int rf = 0; rf < 4; ++rf)
      acc[jf][rf] = (f32x4){0.f, 0.f, 0.f, 0.f};

  const _Float16* wbase = WT + (j0 + lr) * HH + lg * 8;

#pragma unroll 2
  for (int ks = 0; ks < 8; ++ks) {
    half8 b[4];
#pragma unroll
    for (int rf = 0; rf < 4; ++rf)
      b[rf] = *(const half8*)(act + swz(rf * 16 + lr, ks * 32 + lg * 8));
#pragma unroll
    for (int jf = 0; jf < 4; ++jf) {
      half8 a = *(const half8*)(wbase + jf * 16 * HH + ks * 32);
#pragma unroll
      for (int rf = 0; rf < 4; ++rf)
        acc[jf][rf] = __builtin_amdgcn_mfma_f32_16x16x32_f16(a, b[rf], acc[jf][rf], 0, 0, 0);
    }
  }

  __syncthreads();  // all waves done READING act before overwrite

#pragma unroll
  for (int jf = 0; jf < 4; ++jf) {
    f32x4 bj = *(const f32x4*)(bias + j0 + jf * 16 + lg * 4);
#pragma unroll
    for (int rf = 0; rf < 4; ++rf) {
      f32x4 v = acc[jf][rf] + bj;
      half4 h;
#pragma unroll
      for (int u = 0; u < 4; ++u) {
        float x = v[u];
        if (RELU) x = fmaxf(x, 0.f);
        h[u] = (_Float16)x;
      }
      *(half4*)(act + swz(rf * 16 + lr, j0 + jf * 16 + lg * 4)) = h;
    }
  }
  __syncthreads();
}

// layer 1: F=3 -> H (relu). xs = staged coalesced copy of this tile's nodes.
__device__ __forceinline__ void layer1(char* act, const float* xs,
                                       const float* __restrict__ W0,
                                       const float* __restrict__ b0, int tid)
{
  const int j = tid;
  const float w0 = W0[j], w1 = W0[HH + j], w2 = W0[2 * HH + j], b = b0[j];
#pragma unroll 4
  for (int r = 0; r < ROWS; ++r) {
    float a = fmaf(xs[r * 3 + 2], w2,
                   fmaf(xs[r * 3 + 1], w1, fmaf(xs[r * 3], w0, b)));
    a = fmaxf(a, 0.f);
    *(_Float16*)(act + swz(r, j)) = (_Float16)a;
  }
}

// ---------------------------------------------------------------------------
__global__ __launch_bounds__(THREADS, 4)
void trunk_kernel(const float* __restrict__ nodes, const int* __restrict__ coord_seg,
                  const float* __restrict__ tw0, const float* __restrict__ tb0,
                  const _Float16* __restrict__ wt1, const float* __restrict__ tb1,
                  const _Float16* __restrict__ wt2, const float* __restrict__ tb2,
                  float* __restrict__ seg_sum)
{
  __shared__ __align__(16) char act[ROWS * HH * 2];  // 32KB
  __shared__ float xs[ROWS * 3];
  __shared__ int   segs[ROWS];
  const int tid = threadIdx.x;
  const int r0g = blockIdx.x * ROWS;

  if (tid < ROWS * 3) xs[tid] = nodes[r0g * 3 + tid];
  if (tid < ROWS) segs[tid] = coord_seg[r0g + tid];
  __syncthreads();

  layer1(act, xs, tw0, tb0, tid);
  __syncthreads();
  heavy_layer<true >(act, wt1, tb1, tid);
  heavy_layer<false>(act, wt2, tb2, tid);  // c (no relu)

  // per-segment sums of c; segs sorted -> usually 1 distinct per 64-row tile.
  {
    const int j = tid;
    const int s_lo = segs[0], s_hi = segs[ROWS - 1];
    for (int s = s_lo; s <= s_hi; ++s) {
      float p = 0.f;
      for (int r = 0; r < ROWS; ++r)
        if (segs[r] == s)
          p += (float)*(const _Float16*)(act + swz(r, j));
      atomicAdd(&seg_sum[s * HH + j], p);
    }
  }
}

__global__ __launch_bounds__(THREADS, 4)
void branch_kernel(const float* __restrict__ known_nodes, const int* __restrict__ known_seg,
                   const float* __restrict__ bw0, const float* __restrict__ bb0,
                   const _Float16* __restrict__ wt1, const float* __restrict__ bb1,
                   const _Float16* __restrict__ wt2, const float* __restrict__ bb2,
                   const float* __restrict__ seg_mean,
                   const _Float16* __restrict__ wto, const float* __restrict__ ob0,
                   const float* __restrict__ ow1, const float* __restrict__ ob1,
                   float* __restrict__ out)
{
  __shared__ __align__(16) char act[ROWS * HH * 2];  // 32KB
  __shared__ float xs_ps[4 * ROWS * 3];              // xs (layer1) then partials
  __shared__ int   segs[ROWS];
  const int tid = threadIdx.x;
  const int r0g = blockIdx.x * ROWS;

  if (tid < ROWS * 3) xs_ps[tid] = known_nodes[r0g * 3 + tid];
  if (tid < ROWS) segs[tid] = known_seg[r0g + tid];
  __syncthreads();

  layer1(act, xs_ps, bw0, bb0, tid);
  __syncthreads();
  heavy_layer<true >(act, wt1, bb1, tid);
  heavy_layer<false>(act, wt2, bb2, tid);  // f (no relu)

  // feat = f * seg_mean[seg] (in place, fp16); hoist seg_mean per seg-change
  {
    const int j = tid;
    int sprev = -1;
    float sm = 0.f;
    for (int r = 0; r < ROWS; ++r) {
      int s = segs[r];  // wave-uniform
      if (s != sprev) { sm = seg_mean[s * HH + j]; sprev = s; }
      _Float16* p = (_Float16*)(act + swz(r, j));
      *p = (_Float16)((float)*p * sm);
    }
  }
  __syncthreads();

  heavy_layer<true>(act, wto, ob0, tid);  // h = relu(feat @ ow0 + ob0)

  // out = h @ ow1 + ob1 (256 -> 3): all 256 threads, 4 k-quarters in parallel
  {
    const int r = tid & 63;
    const int q = tid >> 6;
    float o0 = 0.f, o1 = 0.f, o2 = 0.f;
    for (int kk = 0; kk < 64; kk += 8) {
      int k0 = q * 64 + kk;
      half8 h = *(const half8*)(act + swz(r, k0));
#pragma unroll
      for (int u = 0; u < 8; ++u) {
        float a = (float)h[u];
        o0 = fmaf(a, ow1[(k0 + u) * 3 + 0], o0);
        o1 = fmaf(a, ow1[(k0 + u) * 3 + 1], o1);
        o2 = fmaf(a, ow1[(k0 + u) * 3 + 2], o2);
      }
    }
    __syncthreads();  // xs_ps reuse
    float* ps = xs_ps + q * ROWS * 3;
    ps[r * 3 + 0] = o0; ps[r * 3 + 1] = o1; ps[r * 3 + 2] = o2;
  }
  __syncthreads();
  if (tid < ROWS) {
    const int r = tid;
    float* dst = out + (size_t)(r0g + r) * 3;
#pragma unroll
    for (int c = 0; c < 3; ++c) {
      float o = ob1[c];
#pragma unroll
      for (int q = 0; q < 4; ++q) o += xs_ps[q * ROWS * 3 + r * 3 + c];
      dst[c] = o;
    }
  }
}

// W[256][256] fp32 row-major -> WT[j][k] fp16 (5 matrices), once per launch.
struct WPtrs { const float* w[5]; _Float16* wt[5]; };
__global__ void transpose_kernel(WPtrs p)
{
  const int m = blockIdx.x >> 8;   // matrix
  const int j = blockIdx.x & 255;  // output row
  const int k = threadIdx.x;       // 256 threads, coalesced writes
  p.wt[m][j * HH + k] = (_Float16)p.w[m][k * HH + j];
}

__global__ void zero_kernel(float* __restrict__ p, int n)
{
  int i = blockIdx.x * blockDim.x + threadIdx.x;
  if (i < n) p[i] = 0.f;
}

__global__ void mean_kernel(const float* __restrict__ seg_sum,
                            const int* __restrict__ coord_seg,
                            float* __restrict__ seg_mean)
{
  const int b = blockIdx.x;
  int lo = 0, n = NTOT;
  while (n > 0) { int h = n >> 1; int mid = lo + h;
    if (coord_seg[mid] < b) { lo = mid + 1; n -= h + 1; } else n = h; }
  int hi = lo; n = NTOT - lo;
  while (n > 0) { int h = n >> 1; int mid = hi + h;
    if (coord_seg[mid] < b + 1) { hi = mid + 1; n -= h + 1; } else n = h; }
  float inv = 1.0f / fmaxf((float)(hi - lo), 1.0f);
  seg_mean[b * HH + threadIdx.x] = seg_sum[b * HH + threadIdx.x] * inv;
}

// ---------------------------------------------------------------------------
extern "C" void kernel_launch(void* const* d_in, const int* in_sizes, int n_in,
                              void* d_out, int out_size, void* d_ws, size_t ws_size,
                              hipStream_t stream)
{
  const float* known_nodes = (const float*)d_in[0];
  const float* nodes       = (const float*)d_in[1];
  const int*   known_seg   = (const int*)d_in[2];
  const int*   coord_seg   = (const int*)d_in[3];
  const float* bw0 = (const float*)d_in[4];
  const float* bb0 = (const float*)d_in[5];
  const float* bw1 = (const float*)d_in[6];
  const float* bb1 = (const float*)d_in[7];
  const float* bw2 = (const float*)d_in[8];
  const float* bb2 = (const float*)d_in[9];
  const float* tw0 = (const float*)d_in[10];
  const float* tb0 = (const float*)d_in[11];
  const float* tw1 = (const float*)d_in[12];
  const float* tb1 = (const float*)d_in[13];
  const float* tw2 = (const float*)d_in[14];
  const float* tb2 = (const float*)d_in[15];
  const float* ow0 = (const float*)d_in[16];
  const float* ob0 = (const float*)d_in[17];
  const float* ow1 = (const float*)d_in[18];
  const float* ob1 = (const float*)d_in[19];

  float* out      = (float*)d_out;
  float* seg_sum  = (float*)d_ws;                        // [64][256] f32
  float* seg_mean = seg_sum + NB * HH;                   // [64][256] f32
  _Float16* wtb   = (_Float16*)((char*)d_ws + (size_t)2 * NB * HH * 4);
  _Float16* wt_tw1 = wtb + 0 * HH * HH;
  _Float16* wt_tw2 = wtb + 1 * HH * HH;
  _Float16* wt_bw1 = wtb + 2 * HH * HH;
  _Float16* wt_bw2 = wtb + 3 * HH * HH;
  _Float16* wt_ow0 = wtb + 4 * HH * HH;

  WPtrs wp;
  wp.w[0] = tw1; wp.wt[0] = wt_tw1;
  wp.w[1] = tw2; wp.wt[1] = wt_tw2;
  wp.w[2] = bw1; wp.wt[2] = wt_bw1;
  wp.w[3] = bw2; wp.wt[3] = wt_bw2;
  wp.w[4] = ow0; wp.wt[4] = wt_ow0;

  transpose_kernel<<<5 * 256, 256, 0, stream>>>(wp);
  zero_kernel<<<(NB * HH + 255) / 256, 256, 0, stream>>>(seg_sum, NB * HH);
  trunk_kernel<<<NTOT / ROWS, THREADS, 0, stream>>>(nodes, coord_seg,
                                                    tw0, tb0, wt_tw1, tb1, wt_tw2, tb2,
                                                    seg_sum);
  mean_kernel<<<NB, 256, 0, stream>>>(seg_sum, coord_seg, seg_mean);
  branch_kernel<<<NTOT / ROWS, THREADS, 0, stream>>>(known_nodes, known_seg,
                                                     bw0, bb0, wt_bw1, bb1, wt_bw2, bb2,
                                                     seg_mean,
                                                     wt_ow0, ob0, ow1, ob1,
                                                     out);
}